// Round 2
// baseline (244.041 us; speedup 1.0000x reference)
//
#include <hip/hip_runtime.h>

#define HW   192
#define HW2  (HW*HW)
#define NPIX (2*HW2)   // B*H*W
#define NUP  (HW*4)

__device__ __forceinline__ float clamp255f(float v){ return fminf(fmaxf(v,0.f),255.f); }

// ---------------------------------------------------------------------------
// Simplex front-end: from pre-conv 4-vector v, compute the 5 LUT indices,
// 5 weights, and table select (LSB w1 / MSB w2). Identical arithmetic to the
// round-0 version that passed.
// ---------------------------------------------------------------------------
__device__ __forceinline__ void simplex_setup(const float v4[4],
    const float* __restrict__ w1m, const float* __restrict__ w2m,
    const float*& tab, int idx[5], float wgt[5])
{
  float f1[4], f2[4]; int i1[4], i2[4];
#pragma unroll
  for (int k=0;k<4;k++){
    float vk = clamp255f(v4[k]);
    int a = (int)(vk*0.0625f);   a = a>15?15:a;   // floor(v/16), clip L1-2
    int b = (int)(vk*0.015625f); b = b>3 ?3 :b;   // floor(v/64), clip L2-2
    i1[k]=a; f1[k]=vk-(float)a*16.f;
    i2[k]=b; f2[k]=vk-(float)b*64.f;
  }
  const int d1=i1[1]-i1[0], d2=i1[2]-i1[0], d3=i1[3]-i1[0];
  const bool within = (d1<=1)&&(d1>=-1)&&(d2<=1)&&(d2>=-1)&&(d3<=1)&&(d3>=-1);

  float ff[4]; int ii[4];
#pragma unroll
  for (int k=0;k<4;k++){ ff[k]= within?f1[k]:f2[k]; ii[k]= within?i1[k]:i2[k]; }
  const float Q    = within?16.f:64.f;
  const float qinv = within?0.0625f:0.015625f;
  tab = within? w1m : w2m;

  // stable-descending ranks (replicates stable argsort(-f))
  const int rk0 = (ff[1]> ff[0]) + (ff[2]> ff[0]) + (ff[3]> ff[0]);
  const int rk1 = (ff[0]>=ff[1]) + (ff[2]> ff[1]) + (ff[3]> ff[1]);
  const int rk2 = (ff[0]>=ff[2]) + (ff[1]>=ff[2]) + (ff[3]> ff[2]);
  const int rk3 = (ff[0]>=ff[3]) + (ff[1]>=ff[3]) + (ff[2]>=ff[3]);

  // sorted (desc) values via min/max network
  float a0=ff[0],a1=ff[1],a2=ff[2],a3=ff[3],t;
  t=fmaxf(a0,a1); a1=fminf(a0,a1); a0=t;
  t=fmaxf(a2,a3); a3=fminf(a2,a3); a2=t;
  t=fmaxf(a0,a2); a2=fminf(a0,a2); a0=t;
  t=fmaxf(a1,a3); a3=fminf(a1,a3); a1=t;
  t=fmaxf(a1,a2); a2=fminf(a1,a2); a1=t;

  wgt[0]=(Q-a0)*qinv; wgt[1]=(a0-a1)*qinv; wgt[2]=(a1-a2)*qinv;
  wgt[3]=(a2-a3)*qinv; wgt[4]=a3*qinv;

#pragma unroll
  for (int t5=0;t5<5;t5++){
    const int c0 = rk0<t5, c1 = rk1<t5, c2 = rk2<t5, c3 = rk3<t5;
    const int A0 = ii[0]+c0;
    const int A1 = within ? (d1 + c1 - c0 + 2) : (ii[1]+c1);
    const int A2 = within ? (d2 + c2 - c0 + 2) : (ii[2]+c2);
    const int A3 = within ? (d3 + c3 - c0 + 2) : (ii[3]+c3);
    idx[t5] = A0*125 + A1*25 + A2*5 + A3;   // ref2index is arange -> linear
  }
}

// stage variant: produce o[OUTC] (keeps round-0 FP order exactly)
template<int OUTC>
__device__ __forceinline__ void interp_eval(const float v4[4],
    const float* __restrict__ w1m, const float* __restrict__ w2m, float* out)
{
  const float* tab; int idx[5]; float wgt[5];
  simplex_setup(v4, w1m, w2m, tab, idx, wgt);
  float s[OUTC];
#pragma unroll
  for (int c=0;c<OUTC;c++) s[c]=0.f;
#pragma unroll
  for (int t5=0;t5<5;t5++){
    const float w = wgt[t5];
    if constexpr (OUTC==2){
      const float2 p = reinterpret_cast<const float2*>(tab)[idx[t5]];
      s[0]=fmaf(w,p.x,s[0]); s[1]=fmaf(w,p.y,s[1]);
    } else {
      s[0]=fmaf(w, tab[idx[t5]], s[0]);
    }
  }
#pragma unroll
  for (int c=0;c<OUTC;c++) out[c]=s[c];
}

// stage6 variant: accumulate the 16-wide LUT rows directly into acc[16]
__device__ __forceinline__ void interp_accum16(const float v4[4],
    const float* __restrict__ w1m, const float* __restrict__ w2m, float acc[16])
{
  const float* tab; int idx[5]; float wgt[5];
  simplex_setup(v4, w1m, w2m, tab, idx, wgt);
#pragma unroll
  for (int t5=0;t5<5;t5++){
    const float w = wgt[t5];
    const float4* row = reinterpret_cast<const float4*>(tab + (size_t)idx[t5]*16);
    float4 p0=row[0], p1=row[1], p2=row[2], p3=row[3];
    acc[0]=fmaf(w,p0.x,acc[0]); acc[1]=fmaf(w,p0.y,acc[1]); acc[2]=fmaf(w,p0.z,acc[2]); acc[3]=fmaf(w,p0.w,acc[3]);
    acc[4]=fmaf(w,p1.x,acc[4]); acc[5]=fmaf(w,p1.y,acc[5]); acc[6]=fmaf(w,p1.z,acc[6]); acc[7]=fmaf(w,p1.w,acc[7]);
    acc[8]=fmaf(w,p2.x,acc[8]); acc[9]=fmaf(w,p2.y,acc[9]); acc[10]=fmaf(w,p2.z,acc[10]); acc[11]=fmaf(w,p2.w,acc[11]);
    acc[12]=fmaf(w,p3.x,acc[12]); acc[13]=fmaf(w,p3.y,acc[13]); acc[14]=fmaf(w,p3.z,acc[14]); acc[15]=fmaf(w,p3.w,acc[15]);
  }
}

// ---------------------------------------------------------------------------
// Stages 1-4: 4 lanes per pixel (one rotation each). The 12-term (m,r) sum
// is reconstructed in exact reference order via quad shuffles, so the value
// fed to rintf is bitwise identical to the round-0 single-thread version.
// ---------------------------------------------------------------------------
template<int OUTC, bool QUANT>
__global__ void __launch_bounds__(256) stage_kernel(
    const float* __restrict__ img, const float* __restrict__ sw,
    const float* __restrict__ w1,  const float* __restrict__ w2,
    const float* __restrict__ res, float* __restrict__ outA, float* __restrict__ outB)
{
  const int t   = blockIdx.x*256 + threadIdx.x;
  const int r   = t & 3;
  const int pix = t >> 2;
  if (pix >= NPIX) return;
  const int b = pix/HW2, rem = pix - b*HW2;
  const int y = rem/HW,  x   = rem - y*HW;
  const float* im = img + b*HW2;

  // rotated, clamped 3x3 taps (rot folded into addressing; same mapping as r0 code)
  float tap[9];
#pragma unroll
  for (int kh=0;kh<3;kh++)
#pragma unroll
    for (int kw=0;kw<3;kw++){
      int ry = (r==0)? y+kh : (r==1)? y+kw : (r==2)? y-kh : y-kw;
      int cx = (r==0)? x+kw : (r==1)? x-kh : (r==2)? x-kw : x+kh;
      ry = min(max(ry,0),HW-1); cx = min(max(cx,0),HW-1);
      float p = im[ry*HW+cx];
      if constexpr (QUANT) p = rintf(clamp255f(p*255.f));
      tap[kh*3+kw]=p;
    }

  float pm[3][OUTC];
#pragma unroll
  for (int m=0;m<3;m++){
    const float* swm = sw + m*36;
    float v[4];
#pragma unroll
    for (int oc=0;oc<4;oc++){
      float a=0.f;
#pragma unroll
      for (int k=0;k<9;k++) a = fmaf(swm[oc*9+k], tap[k], a);
      v[oc]=a;
    }
    float o[OUTC];
    interp_eval<OUTC>(v, w1 + (size_t)m*2125*OUTC, w2 + (size_t)m*625*OUTC, o);
#pragma unroll
    for (int c=0;c<OUTC;c++) pm[m][c] = o[c] + res[m*OUTC+c];
  }

  // exact-order reduction: m0r0, m0r1, ..., m2r3 (matches reference loop)
  const int lane = threadIdx.x & 63;
  const int base = lane & ~3;
  float acc[OUTC];
#pragma unroll
  for (int c=0;c<OUTC;c++) acc[c]=0.f;
#pragma unroll
  for (int m=0;m<3;m++)
#pragma unroll
    for (int rr=0;rr<4;rr++){
#pragma unroll
      for (int c=0;c<OUTC;c++) acc[c] += __shfl(pm[m][c], base+rr, 64);
    }

  if (r==0){
    outA[pix] = rintf(clamp255f((acc[0]/12.0f)*255.0f));
    if constexpr (OUTC==2)
      outB[pix] = rintf(clamp255f((acc[1]/12.0f)*255.0f));
  }
}

// ---------------------------------------------------------------------------
// Stage 6: 16 lanes per pixel: lane = (r<<2)|c. Each lane: 3 interps (m-loop)
// for its (rotation, channel); butterfly over c (xor 1,2), per-r channel
// permutation, butterfly over r (xor 4,8); lane c==0 writes output row 4*by+r.
// ---------------------------------------------------------------------------
__global__ void __launch_bounds__(256) stage6_kernel(
    const float* __restrict__ feat, const float* __restrict__ sw,
    const float* __restrict__ w1,   const float* __restrict__ w2,
    const float* __restrict__ res,  float* __restrict__ out)
{
  const int t   = blockIdx.x*256 + threadIdx.x;
  const int rc  = t & 15;
  const int r   = rc >> 2;
  const int c   = rc & 3;
  const int pix = t >> 4;
  if (pix >= NPIX) return;
  const int b  = pix/HW2, rem = pix - b*HW2;
  const int by = rem/HW,  bx  = rem - by*HW;

  // rotated, clamped 3x3 taps from this lane's channel plane
  const float* im = feat + (size_t)c*NPIX + b*HW2;
  float tap[9];
#pragma unroll
  for (int kh=0;kh<3;kh++)
#pragma unroll
    for (int kw=0;kw<3;kw++){
      int ry = (r==0)? by+kh : (r==1)? by+kw : (r==2)? by-kh : by-kw;
      int cx = (r==0)? bx+kw : (r==1)? bx-kh : (r==2)? bx-kw : bx+kh;
      ry = min(max(ry,0),HW-1); cx = min(max(cx,0),HW-1);
      tap[kh*3+kw] = im[ry*HW+cx];
    }

  float racc[16];
#pragma unroll
  for (int i=0;i<16;i++) racc[i]=0.f;

#pragma unroll
  for (int m=0;m<3;m++){
    const int mc = m*4 + c;
    const float* swmc = sw + mc*36;
    float v[4];
#pragma unroll
    for (int oc=0;oc<4;oc++){
      float a=0.f;
#pragma unroll
      for (int k=0;k<9;k++) a = fmaf(swmc[oc*9+k], tap[k], a);
      v[oc]=a;
    }
    const float* remc = res + mc*16;
#pragma unroll
    for (int i=0;i<16;i++) racc[i] += remc[i];
    interp_accum16(v, w1 + (size_t)mc*2125*16, w2 + (size_t)mc*625*16, racc);
  }

  // reduce over channel lanes (c = low 2 bits)
#pragma unroll
  for (int i=0;i<16;i++){
    racc[i] += __shfl_xor(racc[i],1);
    racc[i] += __shfl_xor(racc[i],2);
  }

  // per-rotation channel permutation (static indices per branch)
  float po[16];
  if (r==0){
#pragma unroll
    for (int i=0;i<16;i++) po[i]=racc[i];
  } else if (r==1){
#pragma unroll
    for (int p=0;p<4;p++)
#pragma unroll
      for (int q=0;q<4;q++) po[p*4+q]=racc[(3-q)*4+p];
  } else if (r==2){
#pragma unroll
    for (int p=0;p<4;p++)
#pragma unroll
      for (int q=0;q<4;q++) po[p*4+q]=racc[(3-p)*4+(3-q)];
  } else {
#pragma unroll
    for (int p=0;p<4;p++)
#pragma unroll
      for (int q=0;q<4;q++) po[p*4+q]=racc[q*4+(3-p)];
  }

  // reduce over rotation lanes (r = bits 2-3)
#pragma unroll
  for (int i=0;i<16;i++){
    po[i] += __shfl_xor(po[i],4);
    po[i] += __shfl_xor(po[i],8);
  }

  if (c==0){
    auto fin = [](float s)->float{
      const float hr = s/48.0f;
      return fminf(fmaxf(hr*255.f,0.f),255.f)/255.f;
    };
    float* op = out + (size_t)b*(NUP*NUP) + (size_t)(4*by+r)*NUP + 4*bx;
    *reinterpret_cast<float4*>(op) =
        make_float4(fin(po[r*4+0]),fin(po[r*4+1]),fin(po[r*4+2]),fin(po[r*4+3]));
  }
}

extern "C" void kernel_launch(void* const* d_in, const int* in_sizes, int n_in,
                              void* d_out, int out_size, void* d_ws, size_t ws_size,
                              hipStream_t stream)
{
  const float* x       = (const float*)d_in[0];
  // d_in[1] = ref2index: arange -> indexing computed analytically, unused
  const float* samp123 = (const float*)d_in[2];
  const float* w1123   = (const float*)d_in[3];
  const float* w2123   = (const float*)d_in[4];
  const float* res123  = (const float*)d_in[5];
  const float* samp4   = (const float*)d_in[6];
  const float* w14     = (const float*)d_in[7];
  const float* w24     = (const float*)d_in[8];
  const float* res4    = (const float*)d_in[9];
  const float* samp6   = (const float*)d_in[10];
  const float* w16     = (const float*)d_in[11];
  const float* w26     = (const float*)d_in[12];
  const float* res6    = (const float*)d_in[13];

  float* ws   = (float*)d_ws;
  float* feat = ws;             // 4 planes of NPIX (refine channels 0..3)
  float* curA = ws + 4*NPIX;
  float* curB = ws + 5*NPIX;

  const int GS = NPIX*4/256;    // 1152 blocks (4 lanes/pixel)
  const int G6 = NPIX*16/256;   // 4608 blocks (16 lanes/pixel)

  // stage strides: samp 3*4*9=108, w1 3*2125*2=12750, w2 3*625*2=3750, res 3*2=6
  stage_kernel<2,true ><<<GS,256,0,stream>>>(x,    samp123,      w1123,        w2123,       res123,    feat,        curB);
  stage_kernel<2,false><<<GS,256,0,stream>>>(curB, samp123+108,  w1123+12750,  w2123+3750,  res123+6,  feat+NPIX,   curA);
  stage_kernel<2,false><<<GS,256,0,stream>>>(curA, samp123+216,  w1123+25500,  w2123+7500,  res123+12, feat+2*NPIX, curB);
  stage_kernel<1,false><<<GS,256,0,stream>>>(curB, samp4,        w14,          w24,         res4,      feat+3*NPIX, nullptr);
  stage6_kernel<<<G6,256,0,stream>>>(feat, samp6, w16, w26, res6, (float*)d_out);
}

// Round 3
// 203.408 us; speedup vs baseline: 1.1998x; 1.1998x over previous
//
#include <hip/hip_runtime.h>

#define HW   192
#define HW2  (HW*HW)
#define NPIX (2*HW2)   // B*H*W
#define NUP  (HW*4)

__device__ __forceinline__ float clamp255f(float v){ return fminf(fmaxf(v,0.f),255.f); }

// ---------------------------------------------------------------------------
// Simplex front-end: from pre-conv 4-vector v, compute the 5 LUT indices,
// 5 weights, and table select (LSB w1 / MSB w2). Arithmetic identical to the
// round-0/1 versions that passed.
// ---------------------------------------------------------------------------
__device__ __forceinline__ void simplex_setup(const float v4[4],
    const float* __restrict__ w1m, const float* __restrict__ w2m,
    const float*& tab, int idx[5], float wgt[5])
{
  float f1[4], f2[4]; int i1[4], i2[4];
#pragma unroll
  for (int k=0;k<4;k++){
    float vk = clamp255f(v4[k]);
    int a = (int)(vk*0.0625f);   a = a>15?15:a;   // floor(v/16), clip L1-2
    int b = (int)(vk*0.015625f); b = b>3 ?3 :b;   // floor(v/64), clip L2-2
    i1[k]=a; f1[k]=vk-(float)a*16.f;
    i2[k]=b; f2[k]=vk-(float)b*64.f;
  }
  const int d1=i1[1]-i1[0], d2=i1[2]-i1[0], d3=i1[3]-i1[0];
  const bool within = (d1<=1)&&(d1>=-1)&&(d2<=1)&&(d2>=-1)&&(d3<=1)&&(d3>=-1);

  float ff[4]; int ii[4];
#pragma unroll
  for (int k=0;k<4;k++){ ff[k]= within?f1[k]:f2[k]; ii[k]= within?i1[k]:i2[k]; }
  const float Q    = within?16.f:64.f;
  const float qinv = within?0.0625f:0.015625f;
  tab = within? w1m : w2m;

  // stable-descending ranks (replicates stable argsort(-f))
  const int rk0 = (ff[1]> ff[0]) + (ff[2]> ff[0]) + (ff[3]> ff[0]);
  const int rk1 = (ff[0]>=ff[1]) + (ff[2]> ff[1]) + (ff[3]> ff[1]);
  const int rk2 = (ff[0]>=ff[2]) + (ff[1]>=ff[2]) + (ff[3]> ff[2]);
  const int rk3 = (ff[0]>=ff[3]) + (ff[1]>=ff[3]) + (ff[2]>=ff[3]);

  // sorted (desc) values via min/max network
  float a0=ff[0],a1=ff[1],a2=ff[2],a3=ff[3],t;
  t=fmaxf(a0,a1); a1=fminf(a0,a1); a0=t;
  t=fmaxf(a2,a3); a3=fminf(a2,a3); a2=t;
  t=fmaxf(a0,a2); a2=fminf(a0,a2); a0=t;
  t=fmaxf(a1,a3); a3=fminf(a1,a3); a1=t;
  t=fmaxf(a1,a2); a2=fminf(a1,a2); a1=t;

  wgt[0]=(Q-a0)*qinv; wgt[1]=(a0-a1)*qinv; wgt[2]=(a1-a2)*qinv;
  wgt[3]=(a2-a3)*qinv; wgt[4]=a3*qinv;

#pragma unroll
  for (int t5=0;t5<5;t5++){
    const int c0 = rk0<t5, c1 = rk1<t5, c2 = rk2<t5, c3 = rk3<t5;
    const int A0 = ii[0]+c0;
    const int A1 = within ? (d1 + c1 - c0 + 2) : (ii[1]+c1);
    const int A2 = within ? (d2 + c2 - c0 + 2) : (ii[2]+c2);
    const int A3 = within ? (d3 + c3 - c0 + 2) : (ii[3]+c3);
    idx[t5] = A0*125 + A1*25 + A2*5 + A3;   // ref2index is arange -> linear
  }
}

// stage variant: produce o[OUTC] (keeps FP order exactly)
template<int OUTC>
__device__ __forceinline__ void interp_eval(const float v4[4],
    const float* __restrict__ w1m, const float* __restrict__ w2m, float* out)
{
  const float* tab; int idx[5]; float wgt[5];
  simplex_setup(v4, w1m, w2m, tab, idx, wgt);
  float s[OUTC];
#pragma unroll
  for (int c=0;c<OUTC;c++) s[c]=0.f;
#pragma unroll
  for (int t5=0;t5<5;t5++){
    const float w = wgt[t5];
    if constexpr (OUTC==2){
      const float2 p = reinterpret_cast<const float2*>(tab)[idx[t5]];
      s[0]=fmaf(w,p.x,s[0]); s[1]=fmaf(w,p.y,s[1]);
    } else {
      s[0]=fmaf(w, tab[idx[t5]], s[0]);
    }
  }
#pragma unroll
  for (int c=0;c<OUTC;c++) out[c]=s[c];
}

// stage6 variant: accumulate the 16-wide LUT rows directly into acc[16]
__device__ __forceinline__ void interp_accum16(const float v4[4],
    const float* __restrict__ w1m, const float* __restrict__ w2m, float acc[16])
{
  const float* tab; int idx[5]; float wgt[5];
  simplex_setup(v4, w1m, w2m, tab, idx, wgt);
#pragma unroll
  for (int t5=0;t5<5;t5++){
    const float w = wgt[t5];
    const float4* row = reinterpret_cast<const float4*>(tab + (size_t)idx[t5]*16);
    float4 p0=row[0], p1=row[1], p2=row[2], p3=row[3];
    acc[0]=fmaf(w,p0.x,acc[0]); acc[1]=fmaf(w,p0.y,acc[1]); acc[2]=fmaf(w,p0.z,acc[2]); acc[3]=fmaf(w,p0.w,acc[3]);
    acc[4]=fmaf(w,p1.x,acc[4]); acc[5]=fmaf(w,p1.y,acc[5]); acc[6]=fmaf(w,p1.z,acc[6]); acc[7]=fmaf(w,p1.w,acc[7]);
    acc[8]=fmaf(w,p2.x,acc[8]); acc[9]=fmaf(w,p2.y,acc[9]); acc[10]=fmaf(w,p2.z,acc[10]); acc[11]=fmaf(w,p2.w,acc[11]);
    acc[12]=fmaf(w,p3.x,acc[12]); acc[13]=fmaf(w,p3.y,acc[13]); acc[14]=fmaf(w,p3.z,acc[14]); acc[15]=fmaf(w,p3.w,acc[15]);
  }
}

// ---------------------------------------------------------------------------
// Stages 1-4: 16 lanes per pixel: lane = (m<<2)|r, lanes with m==3 duplicate
// m=2 (result discarded). The 12-term (m,r) sum is rebuilt in exact reference
// order via 12 sequential shuffles -> value fed to rintf bitwise identical.
// ---------------------------------------------------------------------------
template<int OUTC, bool QUANT>
__global__ void __launch_bounds__(256) stage_kernel(
    const float* __restrict__ img, const float* __restrict__ sw,
    const float* __restrict__ w1,  const float* __restrict__ w2,
    const float* __restrict__ res, float* __restrict__ outA, float* __restrict__ outB)
{
  const int t   = blockIdx.x*256 + threadIdx.x;
  const int r   = t & 3;
  const int m3  = (t >> 2) & 3;
  const int m   = m3 < 3 ? m3 : 2;     // lanes 12-15 duplicate m=2 (discarded)
  const int pix = t >> 4;
  const int b = pix/HW2, rem = pix - b*HW2;
  const int y = rem/HW,  x   = rem - y*HW;
  const float* im = img + b*HW2;

  // rotated, clamped 3x3 taps (rot folded into addressing)
  float tap[9];
#pragma unroll
  for (int kh=0;kh<3;kh++)
#pragma unroll
    for (int kw=0;kw<3;kw++){
      int ry = (r==0)? y+kh : (r==1)? y+kw : (r==2)? y-kh : y-kw;
      int cx = (r==0)? x+kw : (r==1)? x-kh : (r==2)? x-kw : x+kh;
      ry = min(max(ry,0),HW-1); cx = min(max(cx,0),HW-1);
      float p = im[ry*HW+cx];
      if constexpr (QUANT) p = rintf(clamp255f(p*255.f));
      tap[kh*3+kw]=p;
    }

  const float* swm = sw + m*36;
  float v[4];
#pragma unroll
  for (int oc=0;oc<4;oc++){
    float a=0.f;
#pragma unroll
    for (int k=0;k<9;k++) a = fmaf(swm[oc*9+k], tap[k], a);
    v[oc]=a;
  }
  float o[OUTC], pm[OUTC];
  interp_eval<OUTC>(v, w1 + (size_t)m*2125*OUTC, w2 + (size_t)m*625*OUTC, o);
#pragma unroll
  for (int c=0;c<OUTC;c++) pm[c] = o[c] + res[m*OUTC+c];

  // exact-order reduction over the 12 active lanes: j = mm*4+rr in lane order
  const int lane = threadIdx.x & 63;
  const int base = lane & ~15;
  float acc[OUTC];
#pragma unroll
  for (int c=0;c<OUTC;c++) acc[c]=0.f;
#pragma unroll
  for (int j=0;j<12;j++){
#pragma unroll
    for (int c=0;c<OUTC;c++) acc[c] += __shfl(pm[c], base+j, 64);
  }

  if ((lane & 15) == 0){
    outA[pix] = rintf(clamp255f((acc[0]/12.0f)*255.0f));
    if constexpr (OUTC==2)
      outB[pix] = rintf(clamp255f((acc[1]/12.0f)*255.0f));
  }
}

// ---------------------------------------------------------------------------
// Stage 6: block = 256 = 4 waves = 16 pixels. Wave index = channel c, so all
// 64 lanes of a wave gather from ONE (m,c) table per instruction (lanes =
// 16 adjacent pixels x 4 rotations -> correlated indices). Cross-channel
// reduce via padded LDS; permute + rotation butterfly in wave 0.
// ---------------------------------------------------------------------------
__global__ void __launch_bounds__(256) stage6_kernel(
    const float* __restrict__ feat, const float* __restrict__ sw,
    const float* __restrict__ w1,   const float* __restrict__ w2,
    const float* __restrict__ res,  float* __restrict__ out)
{
  __shared__ float lds[4][64][17];   // +1 pad: 17 odd -> conflict-free
  const int lane = threadIdx.x & 63;
  const int c    = threadIdx.x >> 6;     // wave id = channel
  const int r    = lane & 3;
  const int pl   = lane >> 2;            // pixel-local 0..15
  const int pix  = blockIdx.x*16 + pl;
  const int b  = pix/HW2, rem = pix - b*HW2;
  const int by = rem/HW,  bx  = rem - by*HW;

  // rotated, clamped 3x3 taps from this wave's channel plane
  const float* im = feat + (size_t)c*NPIX + b*HW2;
  float tap[9];
#pragma unroll
  for (int kh=0;kh<3;kh++)
#pragma unroll
    for (int kw=0;kw<3;kw++){
      int ry = (r==0)? by+kh : (r==1)? by+kw : (r==2)? by-kh : by-kw;
      int cx = (r==0)? bx+kw : (r==1)? bx-kh : (r==2)? bx-kw : bx+kh;
      ry = min(max(ry,0),HW-1); cx = min(max(cx,0),HW-1);
      tap[kh*3+kw] = im[ry*HW+cx];
    }

  float racc[16];
#pragma unroll
  for (int i=0;i<16;i++) racc[i]=0.f;

#pragma unroll
  for (int m=0;m<3;m++){
    const int mc = m*4 + c;
    const float* swmc = sw + mc*36;
    float v[4];
#pragma unroll
    for (int oc=0;oc<4;oc++){
      float a=0.f;
#pragma unroll
      for (int k=0;k<9;k++) a = fmaf(swmc[oc*9+k], tap[k], a);
      v[oc]=a;
    }
    const float* remc = res + mc*16;
#pragma unroll
    for (int i=0;i<16;i++) racc[i] += remc[i];
    interp_accum16(v, w1 + (size_t)mc*2125*16, w2 + (size_t)mc*625*16, racc);
  }

#pragma unroll
  for (int i=0;i<16;i++) lds[c][lane][i] = racc[i];
  __syncthreads();

  if (c == 0){   // wave-uniform branch: wave 0 finishes
    float s[16];
#pragma unroll
    for (int i=0;i<16;i++)
      s[i] = ((lds[0][lane][i] + lds[1][lane][i]) + lds[2][lane][i]) + lds[3][lane][i];

    // per-rotation channel permutation (static indices per branch)
    float po[16];
    if (r==0){
#pragma unroll
      for (int i=0;i<16;i++) po[i]=s[i];
    } else if (r==1){
#pragma unroll
      for (int p=0;p<4;p++)
#pragma unroll
        for (int q=0;q<4;q++) po[p*4+q]=s[(3-q)*4+p];
    } else if (r==2){
#pragma unroll
      for (int p=0;p<4;p++)
#pragma unroll
        for (int q=0;q<4;q++) po[p*4+q]=s[(3-p)*4+(3-q)];
    } else {
#pragma unroll
      for (int p=0;p<4;p++)
#pragma unroll
        for (int q=0;q<4;q++) po[p*4+q]=s[q*4+(3-p)];
    }

    // reduce over rotation lanes (r = low 2 bits of lane)
#pragma unroll
    for (int i=0;i<16;i++){
      po[i] += __shfl_xor(po[i],1);
      po[i] += __shfl_xor(po[i],2);
    }

    auto fin = [](float sv)->float{
      const float hr = sv/48.0f;
      return fminf(fmaxf(hr*255.f,0.f),255.f)/255.f;
    };
    float* op = out + (size_t)b*(NUP*NUP) + (size_t)(4*by+r)*NUP + 4*bx;
    *reinterpret_cast<float4*>(op) =
        make_float4(fin(po[r*4+0]),fin(po[r*4+1]),fin(po[r*4+2]),fin(po[r*4+3]));
  }
}

extern "C" void kernel_launch(void* const* d_in, const int* in_sizes, int n_in,
                              void* d_out, int out_size, void* d_ws, size_t ws_size,
                              hipStream_t stream)
{
  const float* x       = (const float*)d_in[0];
  // d_in[1] = ref2index: arange -> indexing computed analytically, unused
  const float* samp123 = (const float*)d_in[2];
  const float* w1123   = (const float*)d_in[3];
  const float* w2123   = (const float*)d_in[4];
  const float* res123  = (const float*)d_in[5];
  const float* samp4   = (const float*)d_in[6];
  const float* w14     = (const float*)d_in[7];
  const float* w24     = (const float*)d_in[8];
  const float* res4    = (const float*)d_in[9];
  const float* samp6   = (const float*)d_in[10];
  const float* w16     = (const float*)d_in[11];
  const float* w26     = (const float*)d_in[12];
  const float* res6    = (const float*)d_in[13];

  float* ws   = (float*)d_ws;
  float* feat = ws;             // 4 planes of NPIX (refine channels 0..3)
  float* curA = ws + 4*NPIX;
  float* curB = ws + 5*NPIX;

  const int GS = NPIX*16/256;   // 4608 blocks (16 lanes/pixel)
  const int G6 = NPIX/16;       // 4608 blocks (16 pixels/block, 16 lanes/pixel)

  // stage strides: samp 3*4*9=108, w1 3*2125*2=12750, w2 3*625*2=3750, res 3*2=6
  stage_kernel<2,true ><<<GS,256,0,stream>>>(x,    samp123,      w1123,        w2123,       res123,    feat,        curB);
  stage_kernel<2,false><<<GS,256,0,stream>>>(curB, samp123+108,  w1123+12750,  w2123+3750,  res123+6,  feat+NPIX,   curA);
  stage_kernel<2,false><<<GS,256,0,stream>>>(curA, samp123+216,  w1123+25500,  w2123+7500,  res123+12, feat+2*NPIX, curB);
  stage_kernel<1,false><<<GS,256,0,stream>>>(curB, samp4,        w14,          w24,         res4,      feat+3*NPIX, nullptr);
  stage6_kernel<<<G6,256,0,stream>>>(feat, samp6, w16, w26, res6, (float*)d_out);
}

// Round 7
// 194.299 us; speedup vs baseline: 1.2560x; 1.0469x over previous
//
#include <hip/hip_runtime.h>

#define HW   192
#define HW2  (HW*HW)
#define NPIX (2*HW2)   // B*H*W
#define NUP  (HW*4)

__device__ __forceinline__ float clamp255f(float v){ return fminf(fmaxf(v,0.f),255.f); }

// ---------------------------------------------------------------------------
// Simplex core: from pre-conv 4-vector v, compute `within` flag, 5 LUT row
// indices and 5 weights. Arithmetic identical to rounds 0-3 (passing).
// ---------------------------------------------------------------------------
__device__ __forceinline__ void simplex_core(const float v4[4],
    bool& within_o, int idx[5], float wgt[5])
{
  float f1[4], f2[4]; int i1[4], i2[4];
#pragma unroll
  for (int k=0;k<4;k++){
    float vk = clamp255f(v4[k]);
    int a = (int)(vk*0.0625f);   a = a>15?15:a;   // floor(v/16), clip L1-2
    int b = (int)(vk*0.015625f); b = b>3 ?3 :b;   // floor(v/64), clip L2-2
    i1[k]=a; f1[k]=vk-(float)a*16.f;
    i2[k]=b; f2[k]=vk-(float)b*64.f;
  }
  const int d1=i1[1]-i1[0], d2=i1[2]-i1[0], d3=i1[3]-i1[0];
  const bool within = (d1<=1)&&(d1>=-1)&&(d2<=1)&&(d2>=-1)&&(d3<=1)&&(d3>=-1);
  within_o = within;

  float ff[4]; int ii[4];
#pragma unroll
  for (int k=0;k<4;k++){ ff[k]= within?f1[k]:f2[k]; ii[k]= within?i1[k]:i2[k]; }
  const float Q    = within?16.f:64.f;
  const float qinv = within?0.0625f:0.015625f;

  // stable-descending ranks (replicates stable argsort(-f))
  const int rk0 = (ff[1]> ff[0]) + (ff[2]> ff[0]) + (ff[3]> ff[0]);
  const int rk1 = (ff[0]>=ff[1]) + (ff[2]> ff[1]) + (ff[3]> ff[1]);
  const int rk2 = (ff[0]>=ff[2]) + (ff[1]>=ff[2]) + (ff[3]> ff[2]);
  const int rk3 = (ff[0]>=ff[3]) + (ff[1]>=ff[3]) + (ff[2]>=ff[3]);

  // sorted (desc) values via min/max network
  float a0=ff[0],a1=ff[1],a2=ff[2],a3=ff[3],t;
  t=fmaxf(a0,a1); a1=fminf(a0,a1); a0=t;
  t=fmaxf(a2,a3); a3=fminf(a2,a3); a2=t;
  t=fmaxf(a0,a2); a2=fminf(a0,a2); a0=t;
  t=fmaxf(a1,a3); a3=fminf(a1,a3); a1=t;
  t=fmaxf(a1,a2); a2=fminf(a1,a2); a1=t;

  wgt[0]=(Q-a0)*qinv; wgt[1]=(a0-a1)*qinv; wgt[2]=(a1-a2)*qinv;
  wgt[3]=(a2-a3)*qinv; wgt[4]=a3*qinv;

#pragma unroll
  for (int t5=0;t5<5;t5++){
    const int c0 = rk0<t5, c1 = rk1<t5, c2 = rk2<t5, c3 = rk3<t5;
    const int A0 = ii[0]+c0;
    const int A1 = within ? (d1 + c1 - c0 + 2) : (ii[1]+c1);
    const int A2 = within ? (d2 + c2 - c0 + 2) : (ii[2]+c2);
    const int A3 = within ? (d3 + c3 - c0 + 2) : (ii[3]+c3);
    idx[t5] = A0*125 + A1*25 + A2*5 + A3;   // ref2index is arange -> linear
  }
}

// stage6 variant with pointer select (unchanged from round 3)
__device__ __forceinline__ void interp_accum16(const float v4[4],
    const float* __restrict__ w1m, const float* __restrict__ w2m, float acc[16])
{
  bool within; int idx[5]; float wgt[5];
  simplex_core(v4, within, idx, wgt);
  const float* tab = within ? w1m : w2m;
#pragma unroll
  for (int t5=0;t5<5;t5++){
    const float w = wgt[t5];
    const float4* row = reinterpret_cast<const float4*>(tab + (size_t)idx[t5]*16);
    float4 p0=row[0], p1=row[1], p2=row[2], p3=row[3];
    acc[0]=fmaf(w,p0.x,acc[0]); acc[1]=fmaf(w,p0.y,acc[1]); acc[2]=fmaf(w,p0.z,acc[2]); acc[3]=fmaf(w,p0.w,acc[3]);
    acc[4]=fmaf(w,p1.x,acc[4]); acc[5]=fmaf(w,p1.y,acc[5]); acc[6]=fmaf(w,p1.z,acc[6]); acc[7]=fmaf(w,p1.w,acc[7]);
    acc[8]=fmaf(w,p2.x,acc[8]); acc[9]=fmaf(w,p2.y,acc[9]); acc[10]=fmaf(w,p2.z,acc[10]); acc[11]=fmaf(w,p2.w,acc[11]);
    acc[12]=fmaf(w,p3.x,acc[12]); acc[13]=fmaf(w,p3.y,acc[13]); acc[14]=fmaf(w,p3.z,acc[14]); acc[15]=fmaf(w,p3.w,acc[15]);
  }
}

// ---------------------------------------------------------------------------
// Stages 1-4: 4 lanes per pixel (one rotation each), m serial; w1 tables
// staged in LDS (51KB / 25.5KB), w2 stays global (15KB -> L1-resident).
// 12-term (m,r) sum rebuilt in exact reference order via quad shuffles ->
// value fed to rintf is bitwise identical to the reference order.
// ---------------------------------------------------------------------------
template<int OUTC, bool QUANT>
__global__ void __launch_bounds__(512) stage_kernel(
    const float* __restrict__ img, const float* __restrict__ sw,
    const float* __restrict__ w1,  const float* __restrict__ w2,
    const float* __restrict__ res, float* __restrict__ outA, float* __restrict__ outB)
{
  __shared__ __align__(16) float lds_w1[3*2125*OUTC];
  for (int i = threadIdx.x; i < 3*2125*OUTC; i += 512) lds_w1[i] = w1[i];
  __syncthreads();

  const int t   = blockIdx.x*512 + threadIdx.x;
  const int r   = t & 3;
  const int pix = t >> 2;
  const int b = pix/HW2, rem = pix - b*HW2;
  const int y = rem/HW,  x   = rem - y*HW;
  const float* im = img + b*HW2;

  // rotated, clamped 3x3 taps (rot folded into addressing)
  float tap[9];
#pragma unroll
  for (int kh=0;kh<3;kh++)
#pragma unroll
    for (int kw=0;kw<3;kw++){
      int ry = (r==0)? y+kh : (r==1)? y+kw : (r==2)? y-kh : y-kw;
      int cx = (r==0)? x+kw : (r==1)? x-kh : (r==2)? x-kw : x+kh;
      ry = min(max(ry,0),HW-1); cx = min(max(cx,0),HW-1);
      float p = im[ry*HW+cx];
      if constexpr (QUANT) p = rintf(clamp255f(p*255.f));
      tap[kh*3+kw]=p;
    }

  float pm[3][OUTC];
#pragma unroll
  for (int m=0;m<3;m++){
    const float* swm = sw + m*36;
    float v[4];
#pragma unroll
    for (int oc=0;oc<4;oc++){
      float a=0.f;
#pragma unroll
      for (int k=0;k<9;k++) a = fmaf(swm[oc*9+k], tap[k], a);
      v[oc]=a;
    }

    bool within; int idx[5]; float wgt[5];
    simplex_core(v, within, idx, wgt);

    float s[OUTC];
#pragma unroll
    for (int c=0;c<OUTC;c++) s[c]=0.f;
    if constexpr (OUTC==2){
      const float2* l2 = reinterpret_cast<const float2*>(lds_w1) + m*2125;
      const float2* g2 = reinterpret_cast<const float2*>(w2) + m*625;
      if (within){
#pragma unroll
        for (int t5=0;t5<5;t5++){
          const float2 p = l2[idx[t5]];
          s[0]=fmaf(wgt[t5],p.x,s[0]); s[1]=fmaf(wgt[t5],p.y,s[1]);
        }
      } else {
#pragma unroll
        for (int t5=0;t5<5;t5++){
          const float2 p = g2[idx[t5]];
          s[0]=fmaf(wgt[t5],p.x,s[0]); s[1]=fmaf(wgt[t5],p.y,s[1]);
        }
      }
    } else {
      const float* l1 = lds_w1 + m*2125;
      const float* g1 = w2 + m*625;
      if (within){
#pragma unroll
        for (int t5=0;t5<5;t5++) s[0]=fmaf(wgt[t5], l1[idx[t5]], s[0]);
      } else {
#pragma unroll
        for (int t5=0;t5<5;t5++) s[0]=fmaf(wgt[t5], g1[idx[t5]], s[0]);
      }
    }
#pragma unroll
    for (int c=0;c<OUTC;c++) pm[m][c] = s[c] + res[m*OUTC+c];
  }

  // exact-order reduction: m0r0, m0r1, ..., m2r3 (matches reference loop)
  const int lane = threadIdx.x & 63;
  const int base = lane & ~3;
  float acc[OUTC];
#pragma unroll
  for (int c=0;c<OUTC;c++) acc[c]=0.f;
#pragma unroll
  for (int m=0;m<3;m++)
#pragma unroll
    for (int rr=0;rr<4;rr++){
#pragma unroll
      for (int c=0;c<OUTC;c++) acc[c] += __shfl(pm[m][c], base+rr, 64);
    }

  if (r==0){
    outA[pix] = rintf(clamp255f((acc[0]/12.0f)*255.0f));
    if constexpr (OUTC==2)
      outB[pix] = rintf(clamp255f((acc[1]/12.0f)*255.0f));
  }
}

// ---------------------------------------------------------------------------
// Stage 6 (unchanged from round 3): block = 256 = 4 waves = 16 pixels.
// Wave index = channel c -> one (m,c) table per gather instruction.
// ---------------------------------------------------------------------------
__global__ void __launch_bounds__(256) stage6_kernel(
    const float* __restrict__ feat, const float* __restrict__ sw,
    const float* __restrict__ w1,   const float* __restrict__ w2,
    const float* __restrict__ res,  float* __restrict__ out)
{
  __shared__ float lds[4][64][17];   // +1 pad: 17 odd -> conflict-free
  const int lane = threadIdx.x & 63;
  const int c    = threadIdx.x >> 6;     // wave id = channel
  const int r    = lane & 3;
  const int pl   = lane >> 2;            // pixel-local 0..15
  const int pix  = blockIdx.x*16 + pl;
  const int b  = pix/HW2, rem = pix - b*HW2;
  const int by = rem/HW,  bx  = rem - by*HW;

  // rotated, clamped 3x3 taps from this wave's channel plane
  const float* im = feat + (size_t)c*NPIX + b*HW2;
  float tap[9];
#pragma unroll
  for (int kh=0;kh<3;kh++)
#pragma unroll
    for (int kw=0;kw<3;kw++){
      int ry = (r==0)? by+kh : (r==1)? by+kw : (r==2)? by-kh : by-kw;
      int cx = (r==0)? bx+kw : (r==1)? bx-kh : (r==2)? bx-kw : bx+kh;
      ry = min(max(ry,0),HW-1); cx = min(max(cx,0),HW-1);
      tap[kh*3+kw] = im[ry*HW+cx];
    }

  float racc[16];
#pragma unroll
  for (int i=0;i<16;i++) racc[i]=0.f;

#pragma unroll
  for (int m=0;m<3;m++){
    const int mc = m*4 + c;
    const float* swmc = sw + mc*36;
    float v[4];
#pragma unroll
    for (int oc=0;oc<4;oc++){
      float a=0.f;
#pragma unroll
      for (int k=0;k<9;k++) a = fmaf(swmc[oc*9+k], tap[k], a);
      v[oc]=a;
    }
    const float* remc = res + mc*16;
#pragma unroll
    for (int i=0;i<16;i++) racc[i] += remc[i];
    interp_accum16(v, w1 + (size_t)mc*2125*16, w2 + (size_t)mc*625*16, racc);
  }

#pragma unroll
  for (int i=0;i<16;i++) lds[c][lane][i] = racc[i];
  __syncthreads();

  if (c == 0){   // wave-uniform branch: wave 0 finishes
    float s[16];
#pragma unroll
    for (int i=0;i<16;i++)
      s[i] = ((lds[0][lane][i] + lds[1][lane][i]) + lds[2][lane][i]) + lds[3][lane][i];

    // per-rotation channel permutation (static indices per branch)
    float po[16];
    if (r==0){
#pragma unroll
      for (int i=0;i<16;i++) po[i]=s[i];
    } else if (r==1){
#pragma unroll
      for (int p=0;p<4;p++)
#pragma unroll
        for (int q=0;q<4;q++) po[p*4+q]=s[(3-q)*4+p];
    } else if (r==2){
#pragma unroll
      for (int p=0;p<4;p++)
#pragma unroll
        for (int q=0;q<4;q++) po[p*4+q]=s[(3-p)*4+(3-q)];
    } else {
#pragma unroll
      for (int p=0;p<4;p++)
#pragma unroll
        for (int q=0;q<4;q++) po[p*4+q]=s[q*4+(3-p)];
    }

    // reduce over rotation lanes (r = low 2 bits of lane)
#pragma unroll
    for (int i=0;i<16;i++){
      po[i] += __shfl_xor(po[i],1);
      po[i] += __shfl_xor(po[i],2);
    }

    auto fin = [](float sv)->float{
      const float hr = sv/48.0f;
      return fminf(fmaxf(hr*255.f,0.f),255.f)/255.f;
    };
    float* op = out + (size_t)b*(NUP*NUP) + (size_t)(4*by+r)*NUP + 4*bx;
    *reinterpret_cast<float4*>(op) =
        make_float4(fin(po[r*4+0]),fin(po[r*4+1]),fin(po[r*4+2]),fin(po[r*4+3]));
  }
}

extern "C" void kernel_launch(void* const* d_in, const int* in_sizes, int n_in,
                              void* d_out, int out_size, void* d_ws, size_t ws_size,
                              hipStream_t stream)
{
  const float* x       = (const float*)d_in[0];
  // d_in[1] = ref2index: arange -> indexing computed analytically, unused
  const float* samp123 = (const float*)d_in[2];
  const float* w1123   = (const float*)d_in[3];
  const float* w2123   = (const float*)d_in[4];
  const float* res123  = (const float*)d_in[5];
  const float* samp4   = (const float*)d_in[6];
  const float* w14     = (const float*)d_in[7];
  const float* w24     = (const float*)d_in[8];
  const float* res4    = (const float*)d_in[9];
  const float* samp6   = (const float*)d_in[10];
  const float* w16     = (const float*)d_in[11];
  const float* w26     = (const float*)d_in[12];
  const float* res6    = (const float*)d_in[13];

  float* ws   = (float*)d_ws;
  float* feat = ws;             // 4 planes of NPIX (refine channels 0..3)
  float* curA = ws + 4*NPIX;
  float* curB = ws + 5*NPIX;

  const int GS = NPIX*4/512;    // 576 blocks (4 lanes/pixel, 512 threads)
  const int G6 = NPIX/16;       // 4608 blocks (16 pixels/block, 16 lanes/pixel)

  // stage strides: samp 3*4*9=108, w1 3*2125*2=12750, w2 3*625*2=3750, res 3*2=6
  stage_kernel<2,true ><<<GS,512,0,stream>>>(x,    samp123,      w1123,        w2123,       res123,    feat,        curB);
  stage_kernel<2,false><<<GS,512,0,stream>>>(curB, samp123+108,  w1123+12750,  w2123+3750,  res123+6,  feat+NPIX,   curA);
  stage_kernel<2,false><<<GS,512,0,stream>>>(curA, samp123+216,  w1123+25500,  w2123+7500,  res123+12, feat+2*NPIX, curB);
  stage_kernel<1,false><<<GS,512,0,stream>>>(curB, samp4,        w14,          w24,         res4,      feat+3*NPIX, nullptr);
  stage6_kernel<<<G6,256,0,stream>>>(feat, samp6, w16, w26, res6, (float*)d_out);
}

// Round 8
// 192.582 us; speedup vs baseline: 1.2672x; 1.0089x over previous
//
#include <hip/hip_runtime.h>

#define HW   192
#define HW2  (HW*HW)
#define NPIX (2*HW2)   // B*H*W
#define NUP  (HW*4)

__device__ __forceinline__ float clamp255f(float v){ return fminf(fmaxf(v,0.f),255.f); }

// ---------------------------------------------------------------------------
// Simplex core: from pre-conv 4-vector v, compute `within` flag, 5 LUT row
// indices and 5 weights. Arithmetic identical to rounds 0-7 (passing).
// ---------------------------------------------------------------------------
__device__ __forceinline__ void simplex_core(const float v4[4],
    bool& within_o, int idx[5], float wgt[5])
{
  float f1[4], f2[4]; int i1[4], i2[4];
#pragma unroll
  for (int k=0;k<4;k++){
    float vk = clamp255f(v4[k]);
    int a = (int)(vk*0.0625f);   a = a>15?15:a;   // floor(v/16), clip L1-2
    int b = (int)(vk*0.015625f); b = b>3 ?3 :b;   // floor(v/64), clip L2-2
    i1[k]=a; f1[k]=vk-(float)a*16.f;
    i2[k]=b; f2[k]=vk-(float)b*64.f;
  }
  const int d1=i1[1]-i1[0], d2=i1[2]-i1[0], d3=i1[3]-i1[0];
  const bool within = (d1<=1)&&(d1>=-1)&&(d2<=1)&&(d2>=-1)&&(d3<=1)&&(d3>=-1);
  within_o = within;

  float ff[4]; int ii[4];
#pragma unroll
  for (int k=0;k<4;k++){ ff[k]= within?f1[k]:f2[k]; ii[k]= within?i1[k]:i2[k]; }
  const float Q    = within?16.f:64.f;
  const float qinv = within?0.0625f:0.015625f;

  // stable-descending ranks (replicates stable argsort(-f))
  const int rk0 = (ff[1]> ff[0]) + (ff[2]> ff[0]) + (ff[3]> ff[0]);
  const int rk1 = (ff[0]>=ff[1]) + (ff[2]> ff[1]) + (ff[3]> ff[1]);
  const int rk2 = (ff[0]>=ff[2]) + (ff[1]>=ff[2]) + (ff[3]> ff[2]);
  const int rk3 = (ff[0]>=ff[3]) + (ff[1]>=ff[3]) + (ff[2]>=ff[3]);

  // sorted (desc) values via min/max network
  float a0=ff[0],a1=ff[1],a2=ff[2],a3=ff[3],t;
  t=fmaxf(a0,a1); a1=fminf(a0,a1); a0=t;
  t=fmaxf(a2,a3); a3=fminf(a2,a3); a2=t;
  t=fmaxf(a0,a2); a2=fminf(a0,a2); a0=t;
  t=fmaxf(a1,a3); a3=fminf(a1,a3); a1=t;
  t=fmaxf(a1,a2); a2=fminf(a1,a2); a1=t;

  wgt[0]=(Q-a0)*qinv; wgt[1]=(a0-a1)*qinv; wgt[2]=(a1-a2)*qinv;
  wgt[3]=(a2-a3)*qinv; wgt[4]=a3*qinv;

#pragma unroll
  for (int t5=0;t5<5;t5++){
    const int c0 = rk0<t5, c1 = rk1<t5, c2 = rk2<t5, c3 = rk3<t5;
    const int A0 = ii[0]+c0;
    const int A1 = within ? (d1 + c1 - c0 + 2) : (ii[1]+c1);
    const int A2 = within ? (d2 + c2 - c0 + 2) : (ii[2]+c2);
    const int A3 = within ? (d3 + c3 - c0 + 2) : (ii[3]+c3);
    idx[t5] = A0*125 + A1*25 + A2*5 + A3;   // ref2index is arange -> linear
  }
}

// stage6 variant with pointer select (unchanged from round 3/7)
__device__ __forceinline__ void interp_accum16(const float v4[4],
    const float* __restrict__ w1m, const float* __restrict__ w2m, float acc[16])
{
  bool within; int idx[5]; float wgt[5];
  simplex_core(v4, within, idx, wgt);
  const float* tab = within ? w1m : w2m;
#pragma unroll
  for (int t5=0;t5<5;t5++){
    const float w = wgt[t5];
    const float4* row = reinterpret_cast<const float4*>(tab + (size_t)idx[t5]*16);
    float4 p0=row[0], p1=row[1], p2=row[2], p3=row[3];
    acc[0]=fmaf(w,p0.x,acc[0]); acc[1]=fmaf(w,p0.y,acc[1]); acc[2]=fmaf(w,p0.z,acc[2]); acc[3]=fmaf(w,p0.w,acc[3]);
    acc[4]=fmaf(w,p1.x,acc[4]); acc[5]=fmaf(w,p1.y,acc[5]); acc[6]=fmaf(w,p1.z,acc[6]); acc[7]=fmaf(w,p1.w,acc[7]);
    acc[8]=fmaf(w,p2.x,acc[8]); acc[9]=fmaf(w,p2.y,acc[9]); acc[10]=fmaf(w,p2.z,acc[10]); acc[11]=fmaf(w,p2.w,acc[11]);
    acc[12]=fmaf(w,p3.x,acc[12]); acc[13]=fmaf(w,p3.y,acc[13]); acc[14]=fmaf(w,p3.z,acc[14]); acc[15]=fmaf(w,p3.w,acc[15]);
  }
}

// ---------------------------------------------------------------------------
// Stages 1-4: block = 192 threads = 3 waves = 16 pixels. Wave index = mode m
// (gathers from ONE table per instruction; 64 lanes = 16 adjacent pixels x
// 4 rotations). 1 interp per thread; tables stay in global (w1 ~51KB L2-hot,
// w2 ~15KB L1-hot), non-divergent pointer select. The 12-term (m,r) sum is
// rebuilt in exact reference order (m outer, r inner) via a small LDS buffer
// -> value fed to rintf is bitwise identical to the reference.
// ---------------------------------------------------------------------------
template<int OUTC, bool QUANT>
__global__ void __launch_bounds__(192) stage_kernel(
    const float* __restrict__ img, const float* __restrict__ sw,
    const float* __restrict__ w1,  const float* __restrict__ w2,
    const float* __restrict__ res, float* __restrict__ outA, float* __restrict__ outB)
{
  __shared__ float red[3][64][3];      // [m][lane][c], stride-3 pad
  const int lane = threadIdx.x & 63;
  const int m    = threadIdx.x >> 6;   // wave id = mode, 0..2
  const int r    = lane & 3;
  const int pl   = lane >> 2;          // pixel-local 0..15
  const int pix  = blockIdx.x*16 + pl;
  const int b = pix/HW2, rem = pix - b*HW2;
  const int y = rem/HW,  x   = rem - y*HW;
  const float* im = img + b*HW2;

  // rotated, clamped 3x3 taps (rot folded into addressing)
  float tap[9];
#pragma unroll
  for (int kh=0;kh<3;kh++)
#pragma unroll
    for (int kw=0;kw<3;kw++){
      int ry = (r==0)? y+kh : (r==1)? y+kw : (r==2)? y-kh : y-kw;
      int cx = (r==0)? x+kw : (r==1)? x-kh : (r==2)? x-kw : x+kh;
      ry = min(max(ry,0),HW-1); cx = min(max(cx,0),HW-1);
      float p = im[ry*HW+cx];
      if constexpr (QUANT) p = rintf(clamp255f(p*255.f));
      tap[kh*3+kw]=p;
    }

  // conv for this wave's mode
  const float* swm = sw + m*36;
  float v[4];
#pragma unroll
  for (int oc=0;oc<4;oc++){
    float a=0.f;
#pragma unroll
    for (int k=0;k<9;k++) a = fmaf(swm[oc*9+k], tap[k], a);
    v[oc]=a;
  }

  bool within; int idx[5]; float wgt[5];
  simplex_core(v, within, idx, wgt);

  float s[OUTC];
#pragma unroll
  for (int c=0;c<OUTC;c++) s[c]=0.f;
  if constexpr (OUTC==2){
    const float2* tab = within
        ? reinterpret_cast<const float2*>(w1) + m*2125
        : reinterpret_cast<const float2*>(w2) + m*625;
#pragma unroll
    for (int t5=0;t5<5;t5++){
      const float2 p = tab[idx[t5]];
      s[0]=fmaf(wgt[t5],p.x,s[0]); s[1]=fmaf(wgt[t5],p.y,s[1]);
    }
  } else {
    const float* tab = within ? (w1 + m*2125) : (w2 + m*625);
#pragma unroll
    for (int t5=0;t5<5;t5++) s[0]=fmaf(wgt[t5], tab[idx[t5]], s[0]);
  }

#pragma unroll
  for (int c=0;c<OUTC;c++) red[m][lane][c] = s[c] + res[m*OUTC+c];
  __syncthreads();

  // exact-order reduction: m0r0, m0r1, ..., m2r3 (matches reference loop);
  // wave 0 computes (4x redundant within each quad - broadcast reads), r==0 stores
  if (threadIdx.x < 64){
    const int base = lane & ~3;
    float acc[OUTC];
#pragma unroll
    for (int c=0;c<OUTC;c++) acc[c]=0.f;
#pragma unroll
    for (int mm=0;mm<3;mm++)
#pragma unroll
      for (int rr=0;rr<4;rr++){
#pragma unroll
        for (int c=0;c<OUTC;c++) acc[c] += red[mm][base+rr][c];
      }
    if (r==0){
      outA[pix] = rintf(clamp255f((acc[0]/12.0f)*255.0f));
      if constexpr (OUTC==2)
        outB[pix] = rintf(clamp255f((acc[1]/12.0f)*255.0f));
    }
  }
}

// ---------------------------------------------------------------------------
// Stage 6 (unchanged from round 3/7): block = 256 = 4 waves = 16 pixels.
// Wave index = channel c -> one (m,c) table per gather instruction.
// ---------------------------------------------------------------------------
__global__ void __launch_bounds__(256) stage6_kernel(
    const float* __restrict__ feat, const float* __restrict__ sw,
    const float* __restrict__ w1,   const float* __restrict__ w2,
    const float* __restrict__ res,  float* __restrict__ out)
{
  __shared__ float lds[4][64][17];   // +1 pad: 17 odd -> conflict-free
  const int lane = threadIdx.x & 63;
  const int c    = threadIdx.x >> 6;     // wave id = channel
  const int r    = lane & 3;
  const int pl   = lane >> 2;            // pixel-local 0..15
  const int pix  = blockIdx.x*16 + pl;
  const int b  = pix/HW2, rem = pix - b*HW2;
  const int by = rem/HW,  bx  = rem - by*HW;

  // rotated, clamped 3x3 taps from this wave's channel plane
  const float* im = feat + (size_t)c*NPIX + b*HW2;
  float tap[9];
#pragma unroll
  for (int kh=0;kh<3;kh++)
#pragma unroll
    for (int kw=0;kw<3;kw++){
      int ry = (r==0)? by+kh : (r==1)? by+kw : (r==2)? by-kh : by-kw;
      int cx = (r==0)? bx+kw : (r==1)? bx-kh : (r==2)? bx-kw : bx+kh;
      ry = min(max(ry,0),HW-1); cx = min(max(cx,0),HW-1);
      tap[kh*3+kw] = im[ry*HW+cx];
    }

  float racc[16];
#pragma unroll
  for (int i=0;i<16;i++) racc[i]=0.f;

#pragma unroll
  for (int m=0;m<3;m++){
    const int mc = m*4 + c;
    const float* swmc = sw + mc*36;
    float v[4];
#pragma unroll
    for (int oc=0;oc<4;oc++){
      float a=0.f;
#pragma unroll
      for (int k=0;k<9;k++) a = fmaf(swmc[oc*9+k], tap[k], a);
      v[oc]=a;
    }
    const float* remc = res + mc*16;
#pragma unroll
    for (int i=0;i<16;i++) racc[i] += remc[i];
    interp_accum16(v, w1 + (size_t)mc*2125*16, w2 + (size_t)mc*625*16, racc);
  }

#pragma unroll
  for (int i=0;i<16;i++) lds[c][lane][i] = racc[i];
  __syncthreads();

  if (c == 0){   // wave-uniform branch: wave 0 finishes
    float s[16];
#pragma unroll
    for (int i=0;i<16;i++)
      s[i] = ((lds[0][lane][i] + lds[1][lane][i]) + lds[2][lane][i]) + lds[3][lane][i];

    // per-rotation channel permutation (static indices per branch)
    float po[16];
    if (r==0){
#pragma unroll
      for (int i=0;i<16;i++) po[i]=s[i];
    } else if (r==1){
#pragma unroll
      for (int p=0;p<4;p++)
#pragma unroll
        for (int q=0;q<4;q++) po[p*4+q]=s[(3-q)*4+p];
    } else if (r==2){
#pragma unroll
      for (int p=0;p<4;p++)
#pragma unroll
        for (int q=0;q<4;q++) po[p*4+q]=s[(3-p)*4+(3-q)];
    } else {
#pragma unroll
      for (int p=0;p<4;p++)
#pragma unroll
        for (int q=0;q<4;q++) po[p*4+q]=s[q*4+(3-p)];
    }

    // reduce over rotation lanes (r = low 2 bits of lane)
#pragma unroll
    for (int i=0;i<16;i++){
      po[i] += __shfl_xor(po[i],1);
      po[i] += __shfl_xor(po[i],2);
    }

    auto fin = [](float sv)->float{
      const float hr = sv/48.0f;
      return fminf(fmaxf(hr*255.f,0.f),255.f)/255.f;
    };
    float* op = out + (size_t)b*(NUP*NUP) + (size_t)(4*by+r)*NUP + 4*bx;
    *reinterpret_cast<float4*>(op) =
        make_float4(fin(po[r*4+0]),fin(po[r*4+1]),fin(po[r*4+2]),fin(po[r*4+3]));
  }
}

extern "C" void kernel_launch(void* const* d_in, const int* in_sizes, int n_in,
                              void* d_out, int out_size, void* d_ws, size_t ws_size,
                              hipStream_t stream)
{
  const float* x       = (const float*)d_in[0];
  // d_in[1] = ref2index: arange -> indexing computed analytically, unused
  const float* samp123 = (const float*)d_in[2];
  const float* w1123   = (const float*)d_in[3];
  const float* w2123   = (const float*)d_in[4];
  const float* res123  = (const float*)d_in[5];
  const float* samp4   = (const float*)d_in[6];
  const float* w14     = (const float*)d_in[7];
  const float* w24     = (const float*)d_in[8];
  const float* res4    = (const float*)d_in[9];
  const float* samp6   = (const float*)d_in[10];
  const float* w16     = (const float*)d_in[11];
  const float* w26     = (const float*)d_in[12];
  const float* res6    = (const float*)d_in[13];

  float* ws   = (float*)d_ws;
  float* feat = ws;             // 4 planes of NPIX (refine channels 0..3)
  float* curA = ws + 4*NPIX;
  float* curB = ws + 5*NPIX;

  const int GS = NPIX/16;       // 4608 blocks (16 pixels/block, 192 threads)
  const int G6 = NPIX/16;       // 4608 blocks (16 pixels/block, 16 lanes/pixel)

  // stage strides: samp 3*4*9=108, w1 3*2125*2=12750, w2 3*625*2=3750, res 3*2=6
  stage_kernel<2,true ><<<GS,192,0,stream>>>(x,    samp123,      w1123,        w2123,       res123,    feat,        curB);
  stage_kernel<2,false><<<GS,192,0,stream>>>(curB, samp123+108,  w1123+12750,  w2123+3750,  res123+6,  feat+NPIX,   curA);
  stage_kernel<2,false><<<GS,192,0,stream>>>(curA, samp123+216,  w1123+25500,  w2123+7500,  res123+12, feat+2*NPIX, curB);
  stage_kernel<1,false><<<GS,192,0,stream>>>(curB, samp4,        w14,          w24,         res4,      feat+3*NPIX, nullptr);
  stage6_kernel<<<G6,256,0,stream>>>(feat, samp6, w16, w26, res6, (float*)d_out);
}

// Round 12
// 179.209 us; speedup vs baseline: 1.3618x; 1.0746x over previous
//
#include <hip/hip_runtime.h>

#define HW   192
#define HW2  (HW*HW)
#define NPIX (2*HW2)   // B*H*W
#define NUP  (HW*4)

__device__ __forceinline__ float clamp255f(float v){ return fminf(fmaxf(v,0.f),255.f); }

// ---------------------------------------------------------------------------
// Simplex core: from pre-conv 4-vector v, compute `within` flag, 5 LUT row
// indices and 5 weights. Arithmetic identical to all passing rounds.
// ---------------------------------------------------------------------------
__device__ __forceinline__ void simplex_core(const float v4[4],
    bool& within_o, int idx[5], float wgt[5])
{
  float f1[4], f2[4]; int i1[4], i2[4];
#pragma unroll
  for (int k=0;k<4;k++){
    float vk = clamp255f(v4[k]);
    int a = (int)(vk*0.0625f);   a = a>15?15:a;   // floor(v/16), clip L1-2
    int b = (int)(vk*0.015625f); b = b>3 ?3 :b;   // floor(v/64), clip L2-2
    i1[k]=a; f1[k]=vk-(float)a*16.f;
    i2[k]=b; f2[k]=vk-(float)b*64.f;
  }
  const int d1=i1[1]-i1[0], d2=i1[2]-i1[0], d3=i1[3]-i1[0];
  const bool within = (d1<=1)&&(d1>=-1)&&(d2<=1)&&(d2>=-1)&&(d3<=1)&&(d3>=-1);
  within_o = within;

  float ff[4]; int ii[4];
#pragma unroll
  for (int k=0;k<4;k++){ ff[k]= within?f1[k]:f2[k]; ii[k]= within?i1[k]:i2[k]; }
  const float Q    = within?16.f:64.f;
  const float qinv = within?0.0625f:0.015625f;

  // stable-descending ranks (replicates stable argsort(-f))
  const int rk0 = (ff[1]> ff[0]) + (ff[2]> ff[0]) + (ff[3]> ff[0]);
  const int rk1 = (ff[0]>=ff[1]) + (ff[2]> ff[1]) + (ff[3]> ff[1]);
  const int rk2 = (ff[0]>=ff[2]) + (ff[1]>=ff[2]) + (ff[3]> ff[2]);
  const int rk3 = (ff[0]>=ff[3]) + (ff[1]>=ff[3]) + (ff[2]>=ff[3]);

  // sorted (desc) values via min/max network
  float a0=ff[0],a1=ff[1],a2=ff[2],a3=ff[3],t;
  t=fmaxf(a0,a1); a1=fminf(a0,a1); a0=t;
  t=fmaxf(a2,a3); a3=fminf(a2,a3); a2=t;
  t=fmaxf(a0,a2); a2=fminf(a0,a2); a0=t;
  t=fmaxf(a1,a3); a3=fminf(a1,a3); a1=t;
  t=fmaxf(a1,a2); a2=fminf(a1,a2); a1=t;

  wgt[0]=(Q-a0)*qinv; wgt[1]=(a0-a1)*qinv; wgt[2]=(a1-a2)*qinv;
  wgt[3]=(a2-a3)*qinv; wgt[4]=a3*qinv;

#pragma unroll
  for (int t5=0;t5<5;t5++){
    const int c0 = rk0<t5, c1 = rk1<t5, c2 = rk2<t5, c3 = rk3<t5;
    const int A0 = ii[0]+c0;
    const int A1 = within ? (d1 + c1 - c0 + 2) : (ii[1]+c1);
    const int A2 = within ? (d2 + c2 - c0 + 2) : (ii[2]+c2);
    const int A3 = within ? (d3 + c3 - c0 + 2) : (ii[3]+c3);
    idx[t5] = A0*125 + A1*25 + A2*5 + A3;   // ref2index is arange -> linear
  }
}

// stage variant: produce o[OUTC] (keeps FP order exactly)
template<int OUTC>
__device__ __forceinline__ void interp_eval(const float v4[4],
    const float* __restrict__ w1m, const float* __restrict__ w2m, float* out)
{
  bool within; int idx[5]; float wgt[5];
  simplex_core(v4, within, idx, wgt);
  float s[OUTC];
#pragma unroll
  for (int c=0;c<OUTC;c++) s[c]=0.f;
#pragma unroll
  for (int t5=0;t5<5;t5++){
    const float w = wgt[t5];
    if constexpr (OUTC==2){
      const float2 p = within ? reinterpret_cast<const float2*>(w1m)[idx[t5]]
                              : reinterpret_cast<const float2*>(w2m)[idx[t5]];
      s[0]=fmaf(w,p.x,s[0]); s[1]=fmaf(w,p.y,s[1]);
    } else {
      const float p = within ? w1m[idx[t5]] : w2m[idx[t5]];
      s[0]=fmaf(w, p, s[0]);
    }
  }
#pragma unroll
  for (int c=0;c<OUTC;c++) out[c]=s[c];
}

// stage6 variant: accumulate the 16-wide LUT rows directly into acc[16]
__device__ __forceinline__ void interp_accum16(const float v4[4],
    const float* __restrict__ w1m, const float* __restrict__ w2m, float acc[16])
{
  bool within; int idx[5]; float wgt[5];
  simplex_core(v4, within, idx, wgt);
  const float* tab = within ? w1m : w2m;
#pragma unroll
  for (int t5=0;t5<5;t5++){
    const float w = wgt[t5];
    const float4* row = reinterpret_cast<const float4*>(tab + (size_t)idx[t5]*16);
    float4 p0=row[0], p1=row[1], p2=row[2], p3=row[3];
    acc[0]=fmaf(w,p0.x,acc[0]); acc[1]=fmaf(w,p0.y,acc[1]); acc[2]=fmaf(w,p0.z,acc[2]); acc[3]=fmaf(w,p0.w,acc[3]);
    acc[4]=fmaf(w,p1.x,acc[4]); acc[5]=fmaf(w,p1.y,acc[5]); acc[6]=fmaf(w,p1.z,acc[6]); acc[7]=fmaf(w,p1.w,acc[7]);
    acc[8]=fmaf(w,p2.x,acc[8]); acc[9]=fmaf(w,p2.y,acc[9]); acc[10]=fmaf(w,p2.z,acc[10]); acc[11]=fmaf(w,p2.w,acc[11]);
    acc[12]=fmaf(w,p3.x,acc[12]); acc[13]=fmaf(w,p3.y,acc[13]); acc[14]=fmaf(w,p3.z,acc[14]); acc[15]=fmaf(w,p3.w,acc[15]);
  }
}

// ---------------------------------------------------------------------------
// Stages 1-4 (round-2 structure, best measured 27.4us/stage): 4 lanes per
// pixel (one rotation each), m serial -> gathers are wave-uniform per table.
// 12-term (m,r) sum rebuilt in exact reference order via quad shuffles ->
// value fed to rintf is bitwise identical to the reference.
// ---------------------------------------------------------------------------
template<int OUTC, bool QUANT>
__global__ void __launch_bounds__(256) stage_kernel(
    const float* __restrict__ img, const float* __restrict__ sw,
    const float* __restrict__ w1,  const float* __restrict__ w2,
    const float* __restrict__ res, float* __restrict__ outA, float* __restrict__ outB)
{
  const int t   = blockIdx.x*256 + threadIdx.x;
  const int r   = t & 3;
  const int pix = t >> 2;
  if (pix >= NPIX) return;
  const int b = pix/HW2, rem = pix - b*HW2;
  const int y = rem/HW,  x   = rem - y*HW;
  const float* im = img + b*HW2;

  // rotated, clamped 3x3 taps (rot folded into addressing)
  float tap[9];
#pragma unroll
  for (int kh=0;kh<3;kh++)
#pragma unroll
    for (int kw=0;kw<3;kw++){
      int ry = (r==0)? y+kh : (r==1)? y+kw : (r==2)? y-kh : y-kw;
      int cx = (r==0)? x+kw : (r==1)? x-kh : (r==2)? x-kw : x+kh;
      ry = min(max(ry,0),HW-1); cx = min(max(cx,0),HW-1);
      float p = im[ry*HW+cx];
      if constexpr (QUANT) p = rintf(clamp255f(p*255.f));
      tap[kh*3+kw]=p;
    }

  float pm[3][OUTC];
#pragma unroll
  for (int m=0;m<3;m++){
    const float* swm = sw + m*36;
    float v[4];
#pragma unroll
    for (int oc=0;oc<4;oc++){
      float a=0.f;
#pragma unroll
      for (int k=0;k<9;k++) a = fmaf(swm[oc*9+k], tap[k], a);
      v[oc]=a;
    }
    float o[OUTC];
    interp_eval<OUTC>(v, w1 + (size_t)m*2125*OUTC, w2 + (size_t)m*625*OUTC, o);
#pragma unroll
    for (int c=0;c<OUTC;c++) pm[m][c] = o[c] + res[m*OUTC+c];
  }

  // exact-order reduction: m0r0, m0r1, ..., m2r3 (matches reference loop)
  const int lane = threadIdx.x & 63;
  const int base = lane & ~3;
  float acc[OUTC];
#pragma unroll
  for (int c=0;c<OUTC;c++) acc[c]=0.f;
#pragma unroll
  for (int m=0;m<3;m++)
#pragma unroll
    for (int rr=0;rr<4;rr++){
#pragma unroll
      for (int c=0;c<OUTC;c++) acc[c] += __shfl(pm[m][c], base+rr, 64);
    }

  if (r==0){
    outA[pix] = rintf(clamp255f((acc[0]/12.0f)*255.0f));
    if constexpr (OUTC==2)
      outB[pix] = rintf(clamp255f((acc[1]/12.0f)*255.0f));
  }
}

// ---------------------------------------------------------------------------
// Stage 6 (rounds 3-8 structure, measured 67.5us): block = 4 waves = 16
// pixels. Wave index = channel c -> one (m,c) table per gather instruction.
// ---------------------------------------------------------------------------
__global__ void __launch_bounds__(256) stage6_kernel(
    const float* __restrict__ feat, const float* __restrict__ sw,
    const float* __restrict__ w1,   const float* __restrict__ w2,
    const float* __restrict__ res,  float* __restrict__ out)
{
  __shared__ float lds[4][64][17];   // +1 pad: 17 odd -> conflict-free
  const int lane = threadIdx.x & 63;
  const int c    = threadIdx.x >> 6;     // wave id = channel
  const int r    = lane & 3;
  const int pl   = lane >> 2;            // pixel-local 0..15
  const int pix  = blockIdx.x*16 + pl;
  const int b  = pix/HW2, rem = pix - b*HW2;
  const int by = rem/HW,  bx  = rem - by*HW;

  // rotated, clamped 3x3 taps from this wave's channel plane
  const float* im = feat + (size_t)c*NPIX + b*HW2;
  float tap[9];
#pragma unroll
  for (int kh=0;kh<3;kh++)
#pragma unroll
    for (int kw=0;kw<3;kw++){
      int ry = (r==0)? by+kh : (r==1)? by+kw : (r==2)? by-kh : by-kw;
      int cx = (r==0)? bx+kw : (r==1)? bx-kh : (r==2)? bx-kw : bx+kh;
      ry = min(max(ry,0),HW-1); cx = min(max(cx,0),HW-1);
      tap[kh*3+kw] = im[ry*HW+cx];
    }

  float racc[16];
#pragma unroll
  for (int i=0;i<16;i++) racc[i]=0.f;

#pragma unroll
  for (int m=0;m<3;m++){
    const int mc = m*4 + c;
    const float* swmc = sw + mc*36;
    float v[4];
#pragma unroll
    for (int oc=0;oc<4;oc++){
      float a=0.f;
#pragma unroll
      for (int k=0;k<9;k++) a = fmaf(swmc[oc*9+k], tap[k], a);
      v[oc]=a;
    }
    const float* remc = res + mc*16;
#pragma unroll
    for (int i=0;i<16;i++) racc[i] += remc[i];
    interp_accum16(v, w1 + (size_t)mc*2125*16, w2 + (size_t)mc*625*16, racc);
  }

#pragma unroll
  for (int i=0;i<16;i++) lds[c][lane][i] = racc[i];
  __syncthreads();

  if (c == 0){   // wave-uniform branch: wave 0 finishes
    float s[16];
#pragma unroll
    for (int i=0;i<16;i++)
      s[i] = ((lds[0][lane][i] + lds[1][lane][i]) + lds[2][lane][i]) + lds[3][lane][i];

    // per-rotation channel permutation (static indices per branch)
    float po[16];
    if (r==0){
#pragma unroll
      for (int i=0;i<16;i++) po[i]=s[i];
    } else if (r==1){
#pragma unroll
      for (int p=0;p<4;p++)
#pragma unroll
        for (int q=0;q<4;q++) po[p*4+q]=s[(3-q)*4+p];
    } else if (r==2){
#pragma unroll
      for (int p=0;p<4;p++)
#pragma unroll
        for (int q=0;q<4;q++) po[p*4+q]=s[(3-p)*4+(3-q)];
    } else {
#pragma unroll
      for (int p=0;p<4;p++)
#pragma unroll
        for (int q=0;q<4;q++) po[p*4+q]=s[q*4+(3-p)];
    }

    // reduce over rotation lanes (r = low 2 bits of lane)
#pragma unroll
    for (int i=0;i<16;i++){
      po[i] += __shfl_xor(po[i],1);
      po[i] += __shfl_xor(po[i],2);
    }

    auto fin = [](float sv)->float{
      const float hr = sv/48.0f;
      return fminf(fmaxf(hr*255.f,0.f),255.f)/255.f;
    };
    float* op = out + (size_t)b*(NUP*NUP) + (size_t)(4*by+r)*NUP + 4*bx;
    *reinterpret_cast<float4*>(op) =
        make_float4(fin(po[r*4+0]),fin(po[r*4+1]),fin(po[r*4+2]),fin(po[r*4+3]));
  }
}

extern "C" void kernel_launch(void* const* d_in, const int* in_sizes, int n_in,
                              void* d_out, int out_size, void* d_ws, size_t ws_size,
                              hipStream_t stream)
{
  const float* x       = (const float*)d_in[0];
  // d_in[1] = ref2index: arange -> indexing computed analytically, unused
  const float* samp123 = (const float*)d_in[2];
  const float* w1123   = (const float*)d_in[3];
  const float* w2123   = (const float*)d_in[4];
  const float* res123  = (const float*)d_in[5];
  const float* samp4   = (const float*)d_in[6];
  const float* w14     = (const float*)d_in[7];
  const float* w24     = (const float*)d_in[8];
  const float* res4    = (const float*)d_in[9];
  const float* samp6   = (const float*)d_in[10];
  const float* w16     = (const float*)d_in[11];
  const float* w26     = (const float*)d_in[12];
  const float* res6    = (const float*)d_in[13];

  float* ws   = (float*)d_ws;
  float* feat = ws;             // 4 planes of NPIX (refine channels 0..3)
  float* curA = ws + 4*NPIX;
  float* curB = ws + 5*NPIX;

  const int GS = NPIX*4/256;    // 1152 blocks (4 lanes/pixel, 256 threads)
  const int G6 = NPIX/16;       // 4608 blocks (16 pixels/block, 16 lanes/pixel)

  // stage strides: samp 3*4*9=108, w1 3*2125*2=12750, w2 3*625*2=3750, res 3*2=6
  stage_kernel<2,true ><<<GS,256,0,stream>>>(x,    samp123,      w1123,        w2123,       res123,    feat,        curB);
  stage_kernel<2,false><<<GS,256,0,stream>>>(curB, samp123+108,  w1123+12750,  w2123+3750,  res123+6,  feat+NPIX,   curA);
  stage_kernel<2,false><<<GS,256,0,stream>>>(curA, samp123+216,  w1123+25500,  w2123+7500,  res123+12, feat+2*NPIX, curB);
  stage_kernel<1,false><<<GS,256,0,stream>>>(curB, samp4,        w14,          w24,         res4,      feat+3*NPIX, nullptr);
  stage6_kernel<<<G6,256,0,stream>>>(feat, samp6, w16, w26, res6, (float*)d_out);
}

// Round 13
// 174.379 us; speedup vs baseline: 1.3995x; 1.0277x over previous
//
#include <hip/hip_runtime.h>

#define HW   192
#define HW2  (HW*HW)
#define NPIX (2*HW2)   // B*H*W
#define NUP  (HW*4)

__device__ __forceinline__ float clamp255f(float v){ return fminf(fmaxf(v,0.f),255.f); }

// quad broadcast (QUAD_PERM ds_swizzle): all 4 lanes of an aligned quad get
// lane (base+J)'s value. offset = 0x8000 | (J * 0b01010101).
template<int J>
__device__ __forceinline__ int qb_i(int v){
  return __builtin_amdgcn_ds_swizzle(v, 0x8000 + 0x55*J);
}
template<int J>
__device__ __forceinline__ float qb_f(float v){
  return __int_as_float(qb_i<J>(__float_as_int(v)));
}

// ---------------------------------------------------------------------------
// Simplex core: from pre-conv 4-vector v, compute `within` flag, 5 LUT row
// indices and 5 weights. Arithmetic identical to all passing rounds.
// ---------------------------------------------------------------------------
__device__ __forceinline__ void simplex_core(const float v4[4],
    bool& within_o, int idx[5], float wgt[5])
{
  float f1[4], f2[4]; int i1[4], i2[4];
#pragma unroll
  for (int k=0;k<4;k++){
    float vk = clamp255f(v4[k]);
    int a = (int)(vk*0.0625f);   a = a>15?15:a;   // floor(v/16), clip L1-2
    int b = (int)(vk*0.015625f); b = b>3 ?3 :b;   // floor(v/64), clip L2-2
    i1[k]=a; f1[k]=vk-(float)a*16.f;
    i2[k]=b; f2[k]=vk-(float)b*64.f;
  }
  const int d1=i1[1]-i1[0], d2=i1[2]-i1[0], d3=i1[3]-i1[0];
  const bool within = (d1<=1)&&(d1>=-1)&&(d2<=1)&&(d2>=-1)&&(d3<=1)&&(d3>=-1);
  within_o = within;

  float ff[4]; int ii[4];
#pragma unroll
  for (int k=0;k<4;k++){ ff[k]= within?f1[k]:f2[k]; ii[k]= within?i1[k]:i2[k]; }
  const float Q    = within?16.f:64.f;
  const float qinv = within?0.0625f:0.015625f;

  // stable-descending ranks (replicates stable argsort(-f))
  const int rk0 = (ff[1]> ff[0]) + (ff[2]> ff[0]) + (ff[3]> ff[0]);
  const int rk1 = (ff[0]>=ff[1]) + (ff[2]> ff[1]) + (ff[3]> ff[1]);
  const int rk2 = (ff[0]>=ff[2]) + (ff[1]>=ff[2]) + (ff[3]> ff[2]);
  const int rk3 = (ff[0]>=ff[3]) + (ff[1]>=ff[3]) + (ff[2]>=ff[3]);

  // sorted (desc) values via min/max network
  float a0=ff[0],a1=ff[1],a2=ff[2],a3=ff[3],t;
  t=fmaxf(a0,a1); a1=fminf(a0,a1); a0=t;
  t=fmaxf(a2,a3); a3=fminf(a2,a3); a2=t;
  t=fmaxf(a0,a2); a2=fminf(a0,a2); a0=t;
  t=fmaxf(a1,a3); a3=fminf(a1,a3); a1=t;
  t=fmaxf(a1,a2); a2=fminf(a1,a2); a1=t;

  wgt[0]=(Q-a0)*qinv; wgt[1]=(a0-a1)*qinv; wgt[2]=(a1-a2)*qinv;
  wgt[3]=(a2-a3)*qinv; wgt[4]=a3*qinv;

#pragma unroll
  for (int t5=0;t5<5;t5++){
    const int c0 = rk0<t5, c1 = rk1<t5, c2 = rk2<t5, c3 = rk3<t5;
    const int A0 = ii[0]+c0;
    const int A1 = within ? (d1 + c1 - c0 + 2) : (ii[1]+c1);
    const int A2 = within ? (d2 + c2 - c0 + 2) : (ii[2]+c2);
    const int A3 = within ? (d3 + c3 - c0 + 2) : (ii[3]+c3);
    idx[t5] = A0*125 + A1*25 + A2*5 + A3;   // ref2index is arange -> linear
  }
}

// stage variant: produce o[OUTC] (keeps FP order exactly)
template<int OUTC>
__device__ __forceinline__ void interp_eval(const float v4[4],
    const float* __restrict__ w1m, const float* __restrict__ w2m, float* out)
{
  bool within; int idx[5]; float wgt[5];
  simplex_core(v4, within, idx, wgt);
  float s[OUTC];
#pragma unroll
  for (int c=0;c<OUTC;c++) s[c]=0.f;
#pragma unroll
  for (int t5=0;t5<5;t5++){
    const float w = wgt[t5];
    if constexpr (OUTC==2){
      const float2 p = within ? reinterpret_cast<const float2*>(w1m)[idx[t5]]
                              : reinterpret_cast<const float2*>(w2m)[idx[t5]];
      s[0]=fmaf(w,p.x,s[0]); s[1]=fmaf(w,p.y,s[1]);
    } else {
      const float p = within ? w1m[idx[t5]] : w2m[idx[t5]];
      s[0]=fmaf(w, p, s[0]);
    }
  }
#pragma unroll
  for (int c=0;c<OUTC;c++) out[c]=s[c];
}

// ---------------------------------------------------------------------------
// Stages 1-4 (round-12 structure, verbatim; measured 28us/stage): 4 lanes per
// pixel (one rotation each), m serial -> gathers are wave-uniform per table.
// 12-term (m,r) sum rebuilt in exact reference order via quad shuffles ->
// value fed to rintf is bitwise identical to the reference.
// ---------------------------------------------------------------------------
template<int OUTC, bool QUANT>
__global__ void __launch_bounds__(256) stage_kernel(
    const float* __restrict__ img, const float* __restrict__ sw,
    const float* __restrict__ w1,  const float* __restrict__ w2,
    const float* __restrict__ res, float* __restrict__ outA, float* __restrict__ outB)
{
  const int t   = blockIdx.x*256 + threadIdx.x;
  const int r   = t & 3;
  const int pix = t >> 2;
  if (pix >= NPIX) return;
  const int b = pix/HW2, rem = pix - b*HW2;
  const int y = rem/HW,  x   = rem - y*HW;
  const float* im = img + b*HW2;

  // rotated, clamped 3x3 taps (rot folded into addressing)
  float tap[9];
#pragma unroll
  for (int kh=0;kh<3;kh++)
#pragma unroll
    for (int kw=0;kw<3;kw++){
      int ry = (r==0)? y+kh : (r==1)? y+kw : (r==2)? y-kh : y-kw;
      int cx = (r==0)? x+kw : (r==1)? x-kh : (r==2)? x-kw : x+kh;
      ry = min(max(ry,0),HW-1); cx = min(max(cx,0),HW-1);
      float p = im[ry*HW+cx];
      if constexpr (QUANT) p = rintf(clamp255f(p*255.f));
      tap[kh*3+kw]=p;
    }

  float pm[3][OUTC];
#pragma unroll
  for (int m=0;m<3;m++){
    const float* swm = sw + m*36;
    float v[4];
#pragma unroll
    for (int oc=0;oc<4;oc++){
      float a=0.f;
#pragma unroll
      for (int k=0;k<9;k++) a = fmaf(swm[oc*9+k], tap[k], a);
      v[oc]=a;
    }
    float o[OUTC];
    interp_eval<OUTC>(v, w1 + (size_t)m*2125*OUTC, w2 + (size_t)m*625*OUTC, o);
#pragma unroll
    for (int c=0;c<OUTC;c++) pm[m][c] = o[c] + res[m*OUTC+c];
  }

  // exact-order reduction: m0r0, m0r1, ..., m2r3 (matches reference loop)
  const int lane = threadIdx.x & 63;
  const int base = lane & ~3;
  float acc[OUTC];
#pragma unroll
  for (int c=0;c<OUTC;c++) acc[c]=0.f;
#pragma unroll
  for (int m=0;m<3;m++)
#pragma unroll
    for (int rr=0;rr<4;rr++){
#pragma unroll
      for (int c=0;c<OUTC;c++) acc[c] += __shfl(pm[m][c], base+rr, 64);
    }

  if (r==0){
    outA[pix] = rintf(clamp255f((acc[0]/12.0f)*255.0f));
    if constexpr (OUTC==2)
      outB[pix] = rintf(clamp255f((acc[1]/12.0f)*255.0f));
  }
}

// ---------------------------------------------------------------------------
// Stage 6 with QUAD-COOPERATIVE gathers. Block = 4 waves = 16 pixels; wave =
// channel c (one (m,c) table per gather instruction). Each lane computes
// conv+simplex for ITS rotation r, then the aligned quad (4 rotations of one
// pixel) exchanges within/idx/wgt via QUAD_PERM swizzles; lane r loads the
// r-th 16B quarter of each quad member j's LUT row -> 4 lanes share each
// cache line (16 distinct lines/instruction instead of 64). Lane r holds
// acc[j][k] = channel 4r+k of rotation j; per-channel FMA chains (res then
// 5 vertices per m) are bitwise identical to round 12.
// ---------------------------------------------------------------------------
__global__ void __launch_bounds__(256) stage6_kernel(
    const float* __restrict__ feat, const float* __restrict__ sw,
    const float* __restrict__ w1,   const float* __restrict__ w2,
    const float* __restrict__ res,  float* __restrict__ out)
{
  __shared__ float lds[4][64][17];   // [c][lane][slot], stride 17 -> store-conflict-free
  const int lane = threadIdx.x & 63;
  const int c    = threadIdx.x >> 6;     // wave id = channel
  const int r    = lane & 3;             // rotation of this lane AND its quarter index
  const int pl   = lane >> 2;            // pixel-local 0..15
  const int pix  = blockIdx.x*16 + pl;
  const int b  = pix/HW2, rem = pix - b*HW2;
  const int by = rem/HW,  bx  = rem - by*HW;
  const int r4 = r*4;

  // rotated, clamped 3x3 taps from this wave's channel plane
  const float* im = feat + (size_t)c*NPIX + b*HW2;
  float tap[9];
#pragma unroll
  for (int kh=0;kh<3;kh++)
#pragma unroll
    for (int kw=0;kw<3;kw++){
      int ry = (r==0)? by+kh : (r==1)? by+kw : (r==2)? by-kh : by-kw;
      int cx = (r==0)? bx+kw : (r==1)? bx-kh : (r==2)? bx-kw : bx+kh;
      ry = min(max(ry,0),HW-1); cx = min(max(cx,0),HW-1);
      tap[kh*3+kw] = im[ry*HW+cx];
    }

  // acc[j][k] = channel (4r+k) of rotation j's interp sum for this pixel/channel-plane
  float acc[4][4];
#pragma unroll
  for (int j=0;j<4;j++)
#pragma unroll
    for (int k=0;k<4;k++) acc[j][k]=0.f;

#pragma unroll
  for (int m=0;m<3;m++){
    const int mc = m*4 + c;
    const float* swmc = sw + mc*36;
    float v[4];
#pragma unroll
    for (int oc=0;oc<4;oc++){
      float a=0.f;
#pragma unroll
      for (int k=0;k<9;k++) a = fmaf(swmc[oc*9+k], tap[k], a);
      v[oc]=a;
    }
    // res add first (matches round-12 per-channel chain: res, then 5 vertices)
    const float* remc = res + mc*16;
#pragma unroll
    for (int j=0;j<4;j++)
#pragma unroll
      for (int k=0;k<4;k++) acc[j][k] += remc[r4+k];

    bool within; int idx[5]; float wgt[5];
    simplex_core(v, within, idx, wgt);

    const float* w1mc = w1 + (size_t)mc*2125*16;
    const float* w2mc = w2 + (size_t)mc*625*16;
    const int iwv = within ? 1 : 0;
    const int iw0=qb_i<0>(iwv), iw1=qb_i<1>(iwv), iw2=qb_i<2>(iwv), iw3=qb_i<3>(iwv);
    const float* tb0 = iw0 ? w1mc : w2mc;
    const float* tb1 = iw1 ? w1mc : w2mc;
    const float* tb2 = iw2 ? w1mc : w2mc;
    const float* tb3 = iw3 ? w1mc : w2mc;

#pragma unroll
    for (int t5=0;t5<5;t5++){
      const int i0=qb_i<0>(idx[t5]), i1=qb_i<1>(idx[t5]), i2=qb_i<2>(idx[t5]), i3=qb_i<3>(idx[t5]);
      const float u0=qb_f<0>(wgt[t5]), u1=qb_f<1>(wgt[t5]), u2=qb_f<2>(wgt[t5]), u3=qb_f<3>(wgt[t5]);
      const float4 p0 = *reinterpret_cast<const float4*>(tb0 + (size_t)i0*16 + r4);
      const float4 p1 = *reinterpret_cast<const float4*>(tb1 + (size_t)i1*16 + r4);
      const float4 p2 = *reinterpret_cast<const float4*>(tb2 + (size_t)i2*16 + r4);
      const float4 p3 = *reinterpret_cast<const float4*>(tb3 + (size_t)i3*16 + r4);
      acc[0][0]=fmaf(u0,p0.x,acc[0][0]); acc[0][1]=fmaf(u0,p0.y,acc[0][1]);
      acc[0][2]=fmaf(u0,p0.z,acc[0][2]); acc[0][3]=fmaf(u0,p0.w,acc[0][3]);
      acc[1][0]=fmaf(u1,p1.x,acc[1][0]); acc[1][1]=fmaf(u1,p1.y,acc[1][1]);
      acc[1][2]=fmaf(u1,p1.z,acc[1][2]); acc[1][3]=fmaf(u1,p1.w,acc[1][3]);
      acc[2][0]=fmaf(u2,p2.x,acc[2][0]); acc[2][1]=fmaf(u2,p2.y,acc[2][1]);
      acc[2][2]=fmaf(u2,p2.z,acc[2][2]); acc[2][3]=fmaf(u2,p2.w,acc[2][3]);
      acc[3][0]=fmaf(u3,p3.x,acc[3][0]); acc[3][1]=fmaf(u3,p3.y,acc[3][1]);
      acc[3][2]=fmaf(u3,p3.z,acc[3][2]); acc[3][3]=fmaf(u3,p3.w,acc[3][3]);
    }
  }

  // lane-linear store (conflict-free): slot j*4+k of this lane's row holds
  // channel (4r+k) of rotation j.
#pragma unroll
  for (int j=0;j<4;j++)
#pragma unroll
    for (int k=0;k<4;k++) lds[c][lane][j*4+k] = acc[j][k];
  __syncthreads();

  if (c == 0){   // wave-uniform branch: wave 0 finishes
    // s[i] = channel i of rotation r (this lane's own), summed over c:
    // value lives at row pl*4+(i>>2), slot r*4+(i&3).
    float s[16];
#pragma unroll
    for (int i=0;i<16;i++){
      const int row = (pl<<2) + (i>>2);
      const int col = r4 + (i&3);
      s[i] = ((lds[0][row][col] + lds[1][row][col]) + lds[2][row][col]) + lds[3][row][col];
    }

    // per-rotation channel permutation (static indices per branch)
    float po[16];
    if (r==0){
#pragma unroll
      for (int i=0;i<16;i++) po[i]=s[i];
    } else if (r==1){
#pragma unroll
      for (int p=0;p<4;p++)
#pragma unroll
        for (int q=0;q<4;q++) po[p*4+q]=s[(3-q)*4+p];
    } else if (r==2){
#pragma unroll
      for (int p=0;p<4;p++)
#pragma unroll
        for (int q=0;q<4;q++) po[p*4+q]=s[(3-p)*4+(3-q)];
    } else {
#pragma unroll
      for (int p=0;p<4;p++)
#pragma unroll
        for (int q=0;q<4;q++) po[p*4+q]=s[q*4+(3-p)];
    }

    // reduce over rotation lanes (r = low 2 bits of lane)
#pragma unroll
    for (int i=0;i<16;i++){
      po[i] += __shfl_xor(po[i],1);
      po[i] += __shfl_xor(po[i],2);
    }

    auto fin = [](float sv)->float{
      const float hr = sv/48.0f;
      return fminf(fmaxf(hr*255.f,0.f),255.f)/255.f;
    };
    float* op = out + (size_t)b*(NUP*NUP) + (size_t)(4*by+r)*NUP + 4*bx;
    *reinterpret_cast<float4*>(op) =
        make_float4(fin(po[r*4+0]),fin(po[r*4+1]),fin(po[r*4+2]),fin(po[r*4+3]));
  }
}

extern "C" void kernel_launch(void* const* d_in, const int* in_sizes, int n_in,
                              void* d_out, int out_size, void* d_ws, size_t ws_size,
                              hipStream_t stream)
{
  const float* x       = (const float*)d_in[0];
  // d_in[1] = ref2index: arange -> indexing computed analytically, unused
  const float* samp123 = (const float*)d_in[2];
  const float* w1123   = (const float*)d_in[3];
  const float* w2123   = (const float*)d_in[4];
  const float* res123  = (const float*)d_in[5];
  const float* samp4   = (const float*)d_in[6];
  const float* w14     = (const float*)d_in[7];
  const float* w24     = (const float*)d_in[8];
  const float* res4    = (const float*)d_in[9];
  const float* samp6   = (const float*)d_in[10];
  const float* w16     = (const float*)d_in[11];
  const float* w26     = (const float*)d_in[12];
  const float* res6    = (const float*)d_in[13];

  float* ws   = (float*)d_ws;
  float* feat = ws;             // 4 planes of NPIX (refine channels 0..3)
  float* curA = ws + 4*NPIX;
  float* curB = ws + 5*NPIX;

  const int GS = NPIX*4/256;    // 1152 blocks (4 lanes/pixel, 256 threads)
  const int G6 = NPIX/16;       // 4608 blocks (16 pixels/block, 16 lanes/pixel)

  // stage strides: samp 3*4*9=108, w1 3*2125*2=12750, w2 3*625*2=3750, res 3*2=6
  stage_kernel<2,true ><<<GS,256,0,stream>>>(x,    samp123,      w1123,        w2123,       res123,    feat,        curB);
  stage_kernel<2,false><<<GS,256,0,stream>>>(curB, samp123+108,  w1123+12750,  w2123+3750,  res123+6,  feat+NPIX,   curA);
  stage_kernel<2,false><<<GS,256,0,stream>>>(curA, samp123+216,  w1123+25500,  w2123+7500,  res123+12, feat+2*NPIX, curB);
  stage_kernel<1,false><<<GS,256,0,stream>>>(curB, samp4,        w14,          w24,         res4,      feat+3*NPIX, nullptr);
  stage6_kernel<<<G6,256,0,stream>>>(feat, samp6, w16, w26, res6, (float*)d_out);
}